// Round 8
// baseline (276.112 us; speedup 1.0000x reference)
//
#include <hip/hip_runtime.h>

// x:    (2, 768, 8,8,8)   -> (2,768,512)
// out:  (2, 48, 64,64,64) -> (2,48,262144)
// output: (2, 32, 64,64,64)
constexpr int NCLS = 32;

// ws float offsets
constexpr int WS_POOL = 64;     // 2*768
constexpr int WS_XF  = 1600;    // 2*256
constexpr int WS_PAR = 2112;    // 2*32*153 = 9792
constexpr int WS_P2  = 11904;   // 768 blocks * {sum,sumsq}

typedef float f2 __attribute__((ext_vector_type(2)));

__device__ __forceinline__ float wred(float v) {
#pragma unroll
  for (int off = 32; off > 0; off >>= 1) v += __shfl_down(v, off, 64);
  return v;
}

// packed fp32 helpers (v_pk_fma_f32: halves instruction count vs scalar fp32)
__device__ __forceinline__ f2 pfma(float w, f2 v, f2 a) {
  return __builtin_elementwise_fma((f2)w, v, a);
}
__device__ __forceinline__ f2 paff(f2 v, float sc, float sh) {
  return __builtin_elementwise_fma(v, (f2)sc, (f2)sh);
}
__device__ __forceinline__ f2 prelu(f2 a) {
  return __builtin_elementwise_max(a, (f2)0.f);
}

// K1: 800 blocks. Blocks 0..767: GN2 partial sums (32768 contiguous floats each).
//     Blocks 768..799: GN1 stats + relu-mean pool for one (b,group) (24576 floats).
__global__ void k1_stats(const float* __restrict__ x, const float* __restrict__ oin,
                         const float* __restrict__ g1, const float* __restrict__ b1,
                         float* __restrict__ ws) {
  int t = threadIdx.x;
  int wid = t >> 6, lane = t & 63;
  __shared__ float red[8];
  if (blockIdx.x < 768) {
    int blk = blockIdx.x;
    const float4* p = reinterpret_cast<const float4*>(oin + (size_t)blk * 32768);
    float s = 0.f, s2 = 0.f;
#pragma unroll
    for (int k = 0; k < 32; ++k) {
      float4 v = p[k * 256 + t];
      s  += v.x + v.y + v.z + v.w;
      s2 += v.x*v.x + v.y*v.y + v.z*v.z + v.w*v.w;
    }
    s = wred(s); s2 = wred(s2);
    if (lane == 0) { red[wid*2] = s; red[wid*2+1] = s2; }
    __syncthreads();
    if (t == 0) {
      ws[WS_P2 + blk*2]   = red[0]+red[2]+red[4]+red[6];
      ws[WS_P2 + blk*2+1] = red[1]+red[3]+red[5]+red[7];
    }
  } else {
    int g = blockIdx.x - 768;              // b = g>>4, grp = g&15
    __shared__ float mstat[2];
    const float4* p = reinterpret_cast<const float4*>(x + g * 24576);
    float s = 0.f, s2 = 0.f;
#pragma unroll
    for (int k = 0; k < 24; ++k) {
      float4 v = p[k * 256 + t];
      s  += v.x + v.y + v.z + v.w;
      s2 += v.x*v.x + v.y*v.y + v.z*v.z + v.w*v.w;
    }
    s = wred(s); s2 = wred(s2);
    if (lane == 0) { red[wid*2] = s; red[wid*2+1] = s2; }
    __syncthreads();
    if (t == 0) {
      float S  = red[0]+red[2]+red[4]+red[6];
      float S2 = red[1]+red[3]+red[5]+red[7];
      float mean = S * (1.f/24576.f);
      float var  = S2 * (1.f/24576.f) - mean*mean;
      mstat[0] = mean; mstat[1] = rsqrtf(var + 1e-5f);
    }
    __syncthreads();
    float mean = mstat[0], rstd = mstat[1];
#pragma unroll
    for (int k = 0; k < 12; ++k) {
      int i = k*4 + wid;                   // channel within group [0,48)
      int c = (g & 15) * 48 + i;           // channel [0,768)
      float sc = rstd * g1[c];
      float sh = b1[c] - mean * sc;
      const float* q = x + g * 24576 + i * 512;
      float acc = 0.f;
#pragma unroll
      for (int j = 0; j < 8; ++j)
        acc += fmaxf(fmaf(q[lane + j*64], sc, sh), 0.f);
      acc = wred(acc);
      if (lane == 0) ws[WS_POOL + (g >> 4) * 768 + c] = acc * (1.f/512.f);
    }
  }
}

// K2: x_feat, wave-per-output (coalesced row reads). 512 outputs -> 128 blocks.
__global__ void k2_xfeat(const float* __restrict__ gapw, const float* __restrict__ gapb,
                         float* __restrict__ ws) {
  int wid = threadIdx.x >> 6, lane = threadIdx.x & 63;
  int idx = blockIdx.x * 4 + wid;          // [0,512)
  int b = idx >> 8, o = idx & 255;
  const float* pw = gapw + o * 768;
  const float* pp = ws + WS_POOL + b * 768;
  float s = 0.f;
#pragma unroll
  for (int i = 0; i < 12; ++i) {
    int cc = lane + i*64;
    s += pw[cc] * pp[cc];
  }
  s = wred(s);
  if (lane == 0) ws[WS_XF + idx] = s + gapb[o];
}

// K3: params, wave-per-output (coalesced). 9792 outputs -> 2448 blocks.
// Compact layout: w1 @0..63, w2 @64..127, w3 @128..135, b1 @136..143,
// b2 @144..151, b3 @152.
__global__ void k3_params(const float* __restrict__ cw, const float* __restrict__ cb,
                          const float* __restrict__ te, float* __restrict__ ws) {
  int wid = threadIdx.x >> 6, lane = threadIdx.x & 63;
  int e = blockIdx.x * 4 + wid;            // [0,9792)
  int b = e / (NCLS * 153);
  int r = e % (NCLS * 153);
  int c = r / 153, p = r % 153;
  const float* w  = cw + p * 512;
  const float* xf = ws + WS_XF + b * 256;
  const float* tv = te + c * 256;
  float s = 0.f;
#pragma unroll
  for (int i = 0; i < 4; ++i) {
    int f = lane + i*64;
    s += w[f] * xf[f] + w[256 + f] * tv[f];
  }
  s = wred(s);
  if (lane == 0) ws[WS_PAR + e] = s + cb[p];
}

// K4 v8: fused GN2-finalize + main head.
//  Diagnosis (r0-r7): stall = per-class weight reads SUNK to point-of-use
//  (VGPR 56-68 => ~40 serialized ds_read/s_load waits x ~120-250cyc = ~5000cyc
//  stall per wave-class, invariant to which pipe fetches). Fix = force batch:
//   - stage A (w1+b1, 72f) LDS -> 18 float4 REGISTERS at class top, then
//     sched_barrier(0) so loads can't sink; one latency covers all 18.
//   - stage B (w2/w3/b2/b3, 81f) via wave-uniform s_load (fits SGPR file in
//     one burst; latency hidden under layer1's ~500cyc of pk-fma).
//  8 vox/thread (4 indep FMA chains), 16/16 class split -> 512 blocks,
//  2 waves/SIMD. VGPR ~230 (h0 64 + t1 64 + w1r 72) -> 2 waves sustainable.
__global__ __launch_bounds__(256) void k4_main(const float* __restrict__ oin,
                                               const float* __restrict__ prew,
                                               const float* __restrict__ preb,
                                               const float* __restrict__ g2,
                                               const float* __restrict__ b2,
                                               const float* __restrict__ ws,
                                               float* __restrict__ out) {
  __shared__ __align__(16) float Wl[16 * 80];   // per class: w1[64] + b1[8], stride 80
  __shared__ __align__(16) float prewT[384];
  __shared__ float2 ssl[48];
  __shared__ float ms[64];
  int t = threadIdx.x;
  int b    = blockIdx.x >> 8;        // batch [0,2)
  int rem  = blockIdx.x & 255;
  int tile = rem >> 1;               // [0,128) -> 2048 voxels per tile
  int cls0 = (rem & 1) << 4;         // 0 or 16

  if (t < 32) {
    float S = 0.f, S2 = 0.f;
#pragma unroll
    for (int k = 0; k < 24; ++k) {
      S  += ws[WS_P2 + (t*24 + k)*2];
      S2 += ws[WS_P2 + (t*24 + k)*2 + 1];
    }
    float mean = S * (1.f/786432.f);
    float var  = S2 * (1.f/786432.f) - mean*mean;
    ms[t*2] = mean; ms[t*2+1] = rsqrtf(var + 1e-5f);
  }
  if (t < 128) {
#pragma unroll
    for (int k = 0; k < 3; ++k) {
      int i = t + k*128;
      prewT[(i % 48) * 8 + (i / 48)] = prew[i];
    }
  }
  {
    const float* wsrc = ws + WS_PAR + (size_t)(b * NCLS + cls0) * 153;
#pragma unroll 4
    for (int cc = 0; cc < 16; ++cc)
      if (t < 72) {
        int src = (t < 64) ? t : (136 + t - 64);   // w1 rows then b1
        Wl[cc*80 + t] = wsrc[cc*153 + src];
      }
  }
  __syncthreads();
  if (t < 48) {
    int grp = (b << 4) + t / 3;
    float mean = ms[grp*2], rstd = ms[grp*2+1];
    float sc = rstd * g2[t];
    ssl[t] = make_float2(sc, b2[t] - mean * sc);
  }
  __syncthreads();

  // h0 for 8 voxels: two float4 groups (at +0 and +256 float4s) = 4 f2 pairs
  const float4* ip4 = reinterpret_cast<const float4*>(oin)
                      + (size_t)b * 48 * 65536 + tile*512 + t;
  const float4* pT4 = reinterpret_cast<const float4*>(prewT);
  f2 h0[8][4];
#pragma unroll
  for (int o = 0; o < 8; ++o) {
    float pb = preb[o];
#pragma unroll
    for (int p = 0; p < 4; ++p) h0[o][p] = (f2)pb;
  }
#pragma unroll 8
  for (int c = 0; c < 48; ++c) {
    float4 va = ip4[(size_t)c * 65536];
    float4 vb = ip4[(size_t)c * 65536 + 256];
    float2 ss = ssl[c];
    f2 g[4];
    g[0] = prelu(paff((f2){va.x, va.y}, ss.x, ss.y));
    g[1] = prelu(paff((f2){va.z, va.w}, ss.x, ss.y));
    g[2] = prelu(paff((f2){vb.x, vb.y}, ss.x, ss.y));
    g[3] = prelu(paff((f2){vb.z, vb.w}, ss.x, ss.y));
    float4 w0 = pT4[c*2], w1 = pT4[c*2+1];
    float wv[8] = {w0.x, w0.y, w0.z, w0.w, w1.x, w1.y, w1.z, w1.w};
#pragma unroll
    for (int o = 0; o < 8; ++o)
#pragma unroll
      for (int p = 0; p < 4; ++p) h0[o][p] = pfma(wv[o], g[p], h0[o][p]);
  }

  const float* __restrict__ Wb = ws + WS_PAR + (size_t)(b * NCLS + cls0) * 153;
  float4* op4 = reinterpret_cast<float4*>(out)
                + (size_t)(b * NCLS + cls0) * 65536 + tile*512 + t;
#pragma unroll 1
  for (int cls = 0; cls < 16; ++cls) {
    // --- stage A: batched LDS -> registers (18 x ds_read_b128, issued together)
    const float4* WA = reinterpret_cast<const float4*>(Wl + cls * 80);
    float4 w1r[16];
#pragma unroll
    for (int k = 0; k < 16; ++k) w1r[k] = WA[k];
    float4 b1q0 = WA[16], b1q1 = WA[17];
    __builtin_amdgcn_sched_barrier(0);   // pin loads above the compute
    float b1arr[8] = {b1q0.x,b1q0.y,b1q0.z,b1q0.w,b1q1.x,b1q1.y,b1q1.z,b1q1.w};

    // layer1: t1 = relu(w1 @ h0 + b1)
    f2 t1[8][4];
#pragma unroll
    for (int i = 0; i < 8; ++i) {
      float4 wa = w1r[i*2], wb = w1r[i*2+1];
      float wv[8] = {wa.x, wa.y, wa.z, wa.w, wb.x, wb.y, wb.z, wb.w};
      f2 a[4];
#pragma unroll
      for (int p = 0; p < 4; ++p) a[p] = (f2)b1arr[i];
#pragma unroll
      for (int j = 0; j < 8; ++j)
#pragma unroll
        for (int p = 0; p < 4; ++p) a[p] = pfma(wv[j], h0[j][p], a[p]);
#pragma unroll
      for (int p = 0; p < 4; ++p) t1[i][p] = prelu(a[p]);
    }

    // --- stage B: w2/w3/b2/b3 via wave-uniform s_load (scalar pipe);
    // 81 floats fit the SGPR file in one hoistable burst.
    const float* Wc = Wb + cls * 153;
    float b3v = Wc[152];
    f2 lg[4];
#pragma unroll
    for (int p = 0; p < 4; ++p) lg[p] = (f2)b3v;
#pragma unroll
    for (int i = 0; i < 8; ++i) {
      float bi = Wc[144 + i];
      f2 a[4];
#pragma unroll
      for (int p = 0; p < 4; ++p) a[p] = (f2)bi;
#pragma unroll
      for (int j = 0; j < 8; ++j) {
        float w = Wc[64 + i*8 + j];
#pragma unroll
        for (int p = 0; p < 4; ++p) a[p] = pfma(w, t1[j][p], a[p]);
      }
      float w3 = Wc[128 + i];
#pragma unroll
      for (int p = 0; p < 4; ++p) {
        a[p] = prelu(a[p]);
        lg[p] = pfma(w3, a[p], lg[p]);
      }
    }
    op4[(size_t)cls * 65536]       = make_float4(lg[0].x, lg[0].y, lg[1].x, lg[1].y);
    op4[(size_t)cls * 65536 + 256] = make_float4(lg[2].x, lg[2].y, lg[3].x, lg[3].y);
  }
}

extern "C" void kernel_launch(void* const* d_in, const int* in_sizes, int n_in,
                              void* d_out, int out_size, void* d_ws, size_t ws_size,
                              hipStream_t stream) {
  const float* x    = (const float*)d_in[0];
  const float* oin  = (const float*)d_in[1];
  const float* te   = (const float*)d_in[2];
  const float* g1   = (const float*)d_in[3];
  const float* b1   = (const float*)d_in[4];
  const float* gapw = (const float*)d_in[5];
  const float* gapb = (const float*)d_in[6];
  const float* cw   = (const float*)d_in[7];
  const float* cb   = (const float*)d_in[8];
  const float* g2   = (const float*)d_in[9];
  const float* b2   = (const float*)d_in[10];
  const float* prew = (const float*)d_in[11];
  const float* preb = (const float*)d_in[12];
  float* ws  = (float*)d_ws;
  float* out = (float*)d_out;

  hipLaunchKernelGGL(k1_stats,  dim3(800),  dim3(256), 0, stream, x, oin, g1, b1, ws);
  hipLaunchKernelGGL(k2_xfeat,  dim3(128),  dim3(256), 0, stream, gapw, gapb, ws);
  hipLaunchKernelGGL(k3_params, dim3(2448), dim3(256), 0, stream, cw, cb, te, ws);
  hipLaunchKernelGGL(k4_main,   dim3(512),  dim3(256), 0, stream, oin, prew, preb, g2, b2, ws, out);
}

// Round 10
// 267.713 us; speedup vs baseline: 1.0314x; 1.0314x over previous
//
#include <hip/hip_runtime.h>

// x:    (2, 768, 8,8,8)   -> (2,768,512)
// out:  (2, 48, 64,64,64) -> (2,48,262144)
// output: (2, 32, 64,64,64)
constexpr int NCLS = 32;

// ws float offsets
constexpr int WS_POOL = 64;     // 2*768
constexpr int WS_XF  = 1600;    // 2*256
constexpr int WS_PAR = 2112;    // 2*32*153 = 9792
constexpr int WS_P2  = 11904;   // 768 blocks * {sum,sumsq}

typedef float f2 __attribute__((ext_vector_type(2)));

__device__ __forceinline__ float wred(float v) {
#pragma unroll
  for (int off = 32; off > 0; off >>= 1) v += __shfl_down(v, off, 64);
  return v;
}

// packed fp32 helpers
__device__ __forceinline__ f2 pfma(float w, f2 v, f2 a) {
  return __builtin_elementwise_fma((f2)w, v, a);
}
__device__ __forceinline__ f2 paff(f2 v, float sc, float sh) {
  return __builtin_elementwise_fma(v, (f2)sc, (f2)sh);
}
__device__ __forceinline__ f2 prelu(f2 a) {
  return __builtin_elementwise_max(a, (f2)0.f);
}

// Pin a loaded value into VGPRs at this program point. Ties are per-32-bit
// component (multi-reg float4 ties are unsupported: "tied indirect register").
// The asm DEMANDS each scalar in a VGPR and REDEFINES it, so the compiler
// cannot rematerialize the backing load at a later use (the r8 failure mode).
#define PINF(x) asm volatile("" : "+v"(x))
__device__ __forceinline__ void pin4(float4& v) {
  PINF(v.x); PINF(v.y); PINF(v.z); PINF(v.w);
}

// K1: 800 blocks. Blocks 0..767: GN2 partial sums (32768 contiguous floats each).
//     Blocks 768..799: GN1 stats + relu-mean pool for one (b,group) (24576 floats).
__global__ void k1_stats(const float* __restrict__ x, const float* __restrict__ oin,
                         const float* __restrict__ g1, const float* __restrict__ b1,
                         float* __restrict__ ws) {
  int t = threadIdx.x;
  int wid = t >> 6, lane = t & 63;
  __shared__ float red[8];
  if (blockIdx.x < 768) {
    int blk = blockIdx.x;
    const float4* p = reinterpret_cast<const float4*>(oin + (size_t)blk * 32768);
    float s = 0.f, s2 = 0.f;
#pragma unroll
    for (int k = 0; k < 32; ++k) {
      float4 v = p[k * 256 + t];
      s  += v.x + v.y + v.z + v.w;
      s2 += v.x*v.x + v.y*v.y + v.z*v.z + v.w*v.w;
    }
    s = wred(s); s2 = wred(s2);
    if (lane == 0) { red[wid*2] = s; red[wid*2+1] = s2; }
    __syncthreads();
    if (t == 0) {
      ws[WS_P2 + blk*2]   = red[0]+red[2]+red[4]+red[6];
      ws[WS_P2 + blk*2+1] = red[1]+red[3]+red[5]+red[7];
    }
  } else {
    int g = blockIdx.x - 768;              // b = g>>4, grp = g&15
    __shared__ float mstat[2];
    const float4* p = reinterpret_cast<const float4*>(x + g * 24576);
    float s = 0.f, s2 = 0.f;
#pragma unroll
    for (int k = 0; k < 24; ++k) {
      float4 v = p[k * 256 + t];
      s  += v.x + v.y + v.z + v.w;
      s2 += v.x*v.x + v.y*v.y + v.z*v.z + v.w*v.w;
    }
    s = wred(s); s2 = wred(s2);
    if (lane == 0) { red[wid*2] = s; red[wid*2+1] = s2; }
    __syncthreads();
    if (t == 0) {
      float S  = red[0]+red[2]+red[4]+red[6];
      float S2 = red[1]+red[3]+red[5]+red[7];
      float mean = S * (1.f/24576.f);
      float var  = S2 * (1.f/24576.f) - mean*mean;
      mstat[0] = mean; mstat[1] = rsqrtf(var + 1e-5f);
    }
    __syncthreads();
    float mean = mstat[0], rstd = mstat[1];
#pragma unroll
    for (int k = 0; k < 12; ++k) {
      int i = k*4 + wid;                   // channel within group [0,48)
      int c = (g & 15) * 48 + i;           // channel [0,768)
      float sc = rstd * g1[c];
      float sh = b1[c] - mean * sc;
      const float* q = x + g * 24576 + i * 512;
      float acc = 0.f;
#pragma unroll
      for (int j = 0; j < 8; ++j)
        acc += fmaxf(fmaf(q[lane + j*64], sc, sh), 0.f);
      acc = wred(acc);
      if (lane == 0) ws[WS_POOL + (g >> 4) * 768 + c] = acc * (1.f/512.f);
    }
  }
}

// K2: x_feat, wave-per-output (coalesced row reads). 512 outputs -> 128 blocks.
__global__ void k2_xfeat(const float* __restrict__ gapw, const float* __restrict__ gapb,
                         float* __restrict__ ws) {
  int wid = threadIdx.x >> 6, lane = threadIdx.x & 63;
  int idx = blockIdx.x * 4 + wid;          // [0,512)
  int b = idx >> 8, o = idx & 255;
  const float* pw = gapw + o * 768;
  const float* pp = ws + WS_POOL + b * 768;
  float s = 0.f;
#pragma unroll
  for (int i = 0; i < 12; ++i) {
    int cc = lane + i*64;
    s += pw[cc] * pp[cc];
  }
  s = wred(s);
  if (lane == 0) ws[WS_XF + idx] = s + gapb[o];
}

// K3: params, wave-per-output (coalesced). 9792 outputs -> 2448 blocks.
// Compact layout: w1 @0..63, w2 @64..127, w3 @128..135, b1 @136..143,
// b2 @144..151, b3 @152.
__global__ void k3_params(const float* __restrict__ cw, const float* __restrict__ cb,
                          const float* __restrict__ te, float* __restrict__ ws) {
  int wid = threadIdx.x >> 6, lane = threadIdx.x & 63;
  int e = blockIdx.x * 4 + wid;            // [0,9792)
  int b = e / (NCLS * 153);
  int r = e % (NCLS * 153);
  int c = r / 153, p = r % 153;
  const float* w  = cw + p * 512;
  const float* xf = ws + WS_XF + b * 256;
  const float* tv = te + c * 256;
  float s = 0.f;
#pragma unroll
  for (int i = 0; i < 4; ++i) {
    int f = lane + i*64;
    s += w[f] * xf[f] + w[256 + f] * tv[f];
  }
  s = wred(s);
  if (lane == 0) ws[WS_PAR + e] = s + cb[p];
}

// K4 v9b: fused GN2-finalize + main head.
//  Diagnosis locked (r0-r8): stall = weight loads issued at point-of-use,
//  ~40 serialized lgkm waits per (wave,class). r8's reg-batch was defeated by
//  rematerialization (VGPR 92 < live state). Fix: component-wise PIN forces
//  each value into a VGPR at the pin point. Two pinned groups per class,
//  software-pipelined:
//   A (w1+b1, 18xf4): materialized at class top, PREFETCHED during prev
//     class's layer2 -> steady-state wait ~0.
//   B (w2/w3/b2/b3, 21xf4): issued before layer1, materialized after ->
//     latency hidden under ~600cyc of fma.
//  Base config = r4 (best, 83us): 4 vox/thread, ALL 32 classes, 512 blocks,
//  weights in LDS, pk math. launch_bounds(256,2) caps VGPR at 256 (state ~245).
__global__ __launch_bounds__(256, 2) void k4_main(const float* __restrict__ oin,
                                                  const float* __restrict__ prew,
                                                  const float* __restrict__ preb,
                                                  const float* __restrict__ g2,
                                                  const float* __restrict__ b2,
                                                  const float* __restrict__ ws,
                                                  float* __restrict__ out) {
  __shared__ __align__(16) float Wl[NCLS * 160];   // 32 classes, 160-float stride
  __shared__ __align__(16) float prewT[384];
  __shared__ float2 ssl[48];
  __shared__ float ms[64];
  int t = threadIdx.x;
  int b    = blockIdx.x >> 8;        // batch [0,2)
  int tile = blockIdx.x & 255;       // [0,256) -> 1024 voxels per tile

  if (t < 32) {
    float S = 0.f, S2 = 0.f;
#pragma unroll
    for (int k = 0; k < 24; ++k) {
      S  += ws[WS_P2 + (t*24 + k)*2];
      S2 += ws[WS_P2 + (t*24 + k)*2 + 1];
    }
    float mean = S * (1.f/786432.f);
    float var  = S2 * (1.f/786432.f) - mean*mean;
    ms[t*2] = mean; ms[t*2+1] = rsqrtf(var + 1e-5f);
  }
  if (t < 128) {
#pragma unroll
    for (int k = 0; k < 3; ++k) {
      int i = t + k*128;
      prewT[(i % 48) * 8 + (i / 48)] = prew[i];
    }
  }
  {
    const float* wsrc = ws + WS_PAR + (size_t)b * NCLS * 153;
#pragma unroll 4
    for (int cc = 0; cc < NCLS; ++cc)
      if (t < 153) Wl[cc*160 + t] = wsrc[cc*153 + t];
  }
  __syncthreads();
  if (t < 48) {
    int grp = (b << 4) + t / 3;
    float mean = ms[grp*2], rstd = ms[grp*2+1];
    float sc = rstd * g2[t];
    ssl[t] = make_float2(sc, b2[t] - mean * sc);
  }
  __syncthreads();

  // h0 for 4 voxels (one float4 = 2 f2)
  const float4* ip4 = reinterpret_cast<const float4*>(oin)
                      + (size_t)b * 48 * 65536 + tile*256 + t;
  const float4* pT4 = reinterpret_cast<const float4*>(prewT);
  f2 h0[8][2];
#pragma unroll
  for (int o = 0; o < 8; ++o) {
    float pb = preb[o];
    h0[o][0] = (f2)pb; h0[o][1] = (f2)pb;
  }
#pragma unroll 8
  for (int c = 0; c < 48; ++c) {
    float4 v = ip4[(size_t)c * 65536];
    float2 ss = ssl[c];
    f2 g0 = prelu(paff((f2){v.x, v.y}, ss.x, ss.y));
    f2 g1 = prelu(paff((f2){v.z, v.w}, ss.x, ss.y));
    float4 w0 = pT4[c*2], w1 = pT4[c*2+1];
    float wv[8] = {w0.x, w0.y, w0.z, w0.w, w1.x, w1.y, w1.z, w1.w};
#pragma unroll
    for (int o = 0; o < 8; ++o) {
      h0[o][0] = pfma(wv[o], g0, h0[o][0]);
      h0[o][1] = pfma(wv[o], g1, h0[o][1]);
    }
  }

  // ---- per-class head, software-pipelined pinned weight batches ----
  float4* op4 = reinterpret_cast<float4*>(out)
                + (size_t)b * NCLS * 65536 + tile*256 + t;

  float4 w1A[18];                       // A group: w1 (16) + b1 (2)
  {
    const float4* W0 = reinterpret_cast<const float4*>(Wl);
#pragma unroll
    for (int k = 0; k < 16; ++k) w1A[k] = W0[k];
    w1A[16] = W0[34]; w1A[17] = W0[35];
  }

#pragma unroll 1
  for (int cls = 0; cls < NCLS; ++cls) {
    // materialize A(cls): one batched wait (loads issued a full phase earlier)
#pragma unroll
    for (int k = 0; k < 18; ++k) pin4(w1A[k]);
    __builtin_amdgcn_sched_barrier(0);

    // issue B(cls): w2 (16), w3 (2), b2 (2), b3 (1) — no wait yet
    const float4* W4 = reinterpret_cast<const float4*>(Wl + cls * 160);
    float4 Bv[21];
#pragma unroll
    for (int k = 0; k < 16; ++k) Bv[k] = W4[16 + k];
    Bv[16] = W4[32]; Bv[17] = W4[33];
    Bv[18] = W4[36]; Bv[19] = W4[37];
    Bv[20] = W4[38];
    __builtin_amdgcn_sched_barrier(0);

    // layer1: t1 = relu(w1 @ h0 + b1)   (B latency hides under this)
    float b1arr[8] = {w1A[16].x, w1A[16].y, w1A[16].z, w1A[16].w,
                      w1A[17].x, w1A[17].y, w1A[17].z, w1A[17].w};
    f2 t1[8][2];
#pragma unroll
    for (int i = 0; i < 8; ++i) {
      float4 wa = w1A[i*2], wb = w1A[i*2+1];
      float wv[8] = {wa.x, wa.y, wa.z, wa.w, wb.x, wb.y, wb.z, wb.w};
      f2 a0 = (f2)b1arr[i], a1 = (f2)b1arr[i];
#pragma unroll
      for (int j = 0; j < 8; ++j) {
        a0 = pfma(wv[j], h0[j][0], a0);
        a1 = pfma(wv[j], h0[j][1], a1);
      }
      t1[i][0] = prelu(a0); t1[i][1] = prelu(a1);
    }

    // materialize B(cls)
#pragma unroll
    for (int k = 0; k < 21; ++k) pin4(Bv[k]);
    __builtin_amdgcn_sched_barrier(0);

    // prefetch A(cls+1) — issued here, waited at next iteration's top
    {
      const float4* Wn = reinterpret_cast<const float4*>(Wl + ((cls + 1) & (NCLS - 1)) * 160);
#pragma unroll
      for (int k = 0; k < 16; ++k) w1A[k] = Wn[k];
      w1A[16] = Wn[34]; w1A[17] = Wn[35];
    }
    __builtin_amdgcn_sched_barrier(0);

    // layer2 + layer3 fused   (A(cls+1) latency hides under this)
    float b2arr[8] = {Bv[18].x, Bv[18].y, Bv[18].z, Bv[18].w,
                      Bv[19].x, Bv[19].y, Bv[19].z, Bv[19].w};
    float w3arr[8] = {Bv[16].x, Bv[16].y, Bv[16].z, Bv[16].w,
                      Bv[17].x, Bv[17].y, Bv[17].z, Bv[17].w};
    float b3v = Bv[20].x;
    f2 lg0 = (f2)b3v, lg1 = (f2)b3v;
#pragma unroll
    for (int i = 0; i < 8; ++i) {
      float4 wa = Bv[i*2], wb = Bv[i*2+1];
      float wv[8] = {wa.x, wa.y, wa.z, wa.w, wb.x, wb.y, wb.z, wb.w};
      f2 a0 = (f2)b2arr[i], a1 = (f2)b2arr[i];
#pragma unroll
      for (int j = 0; j < 8; ++j) {
        a0 = pfma(wv[j], t1[j][0], a0);
        a1 = pfma(wv[j], t1[j][1], a1);
      }
      a0 = prelu(a0); a1 = prelu(a1);
      lg0 = pfma(w3arr[i], a0, lg0);
      lg1 = pfma(w3arr[i], a1, lg1);
    }
    op4[(size_t)cls * 65536] = make_float4(lg0.x, lg0.y, lg1.x, lg1.y);
  }
}

extern "C" void kernel_launch(void* const* d_in, const int* in_sizes, int n_in,
                              void* d_out, int out_size, void* d_ws, size_t ws_size,
                              hipStream_t stream) {
  const float* x    = (const float*)d_in[0];
  const float* oin  = (const float*)d_in[1];
  const float* te   = (const float*)d_in[2];
  const float* g1   = (const float*)d_in[3];
  const float* b1   = (const float*)d_in[4];
  const float* gapw = (const float*)d_in[5];
  const float* gapb = (const float*)d_in[6];
  const float* cw   = (const float*)d_in[7];
  const float* cb   = (const float*)d_in[8];
  const float* g2   = (const float*)d_in[9];
  const float* b2   = (const float*)d_in[10];
  const float* prew = (const float*)d_in[11];
  const float* preb = (const float*)d_in[12];
  float* ws  = (float*)d_ws;
  float* out = (float*)d_out;

  hipLaunchKernelGGL(k1_stats,  dim3(800),  dim3(256), 0, stream, x, oin, g1, b1, ws);
  hipLaunchKernelGGL(k2_xfeat,  dim3(128),  dim3(256), 0, stream, gapw, gapb, ws);
  hipLaunchKernelGGL(k3_params, dim3(2448), dim3(256), 0, stream, cw, cb, te, ws);
  hipLaunchKernelGGL(k4_main,   dim3(512),  dim3(256), 0, stream, oin, prew, preb, g2, b2, ws, out);
}